// Round 12
// baseline (245.594 us; speedup 1.0000x reference)
//
#include <hip/hip_runtime.h>
#include <stdint.h>

#define N_Q   65536
#define N_S   65536
#define NB_H  26
#define PAD_H 28
#define KP    10
#define CIN   64
#define COUT  128
#define MT    16   // query points per block
#define BM    16   // output rows per block

typedef unsigned short u16x8  __attribute__((ext_vector_type(8)));
typedef float          f32x4  __attribute__((ext_vector_type(4)));
typedef _Float16       f16x8  __attribute__((ext_vector_type(8)));
typedef _Float16       f16x2  __attribute__((ext_vector_type(2)));
typedef unsigned int   u32x4  __attribute__((ext_vector_type(4)));
typedef unsigned int   u32x2  __attribute__((ext_vector_type(2)));

#define CVT_BLOCKS 2049   // ceil((N_S+1)*CIN/8 / 256)
#define PACK_BLOCKS 40    // ceil(8*20*64 / 256)

static __device__ __forceinline__ unsigned short f2h(float f) {
  return __builtin_bit_cast(unsigned short, (_Float16)f);
}

// v_cvt_pkrtz_f16_f32 packed to raw u32
static __device__ __forceinline__ unsigned int pkrtz_u32(float a, float b) {
  return __builtin_bit_cast(unsigned int, __builtin_amdgcn_cvt_pkrtz(a, b));
}

// half2-dot with fp32 accumulate: v_dot2_f32_f16
static __device__ __forceinline__ float fdot2u(unsigned int a, unsigned int b, float c) {
#if __has_builtin(__builtin_amdgcn_fdot2)
  return __builtin_amdgcn_fdot2(__builtin_bit_cast(f16x2, a),
                                __builtin_bit_cast(f16x2, b), c, false);
#else
  f16x2 ha = __builtin_bit_cast(f16x2, a), hb = __builtin_bit_cast(f16x2, b);
  return c + (float)ha[0] * (float)hb[0] + (float)ha[1] * (float)hb[1];
#endif
}

// ---- prep: x fp32 -> fp16 (+ zero shadow row) AND weight pack (fp16) --------
// (R11 lesson: direct fp32 gather doubles FETCH and costs 24us; the xh fp16
// staging pass is worth its ~2us. Restored to the R9 best config.)
__global__ void prep_kernel(const float* __restrict__ x,
                            const float* __restrict__ w,
                            unsigned short* __restrict__ xh,
                            unsigned short* __restrict__ bp) {
  if (blockIdx.x < CVT_BLOCKS) {
    long t = (long)blockIdx.x * blockDim.x + threadIdx.x;
    long off = t * 8;
    if (off >= (long)(N_S + 1) * CIN) return;
    u16x8 o;
    if (off < (long)N_S * CIN) {
      f32x4 a = *(const f32x4*)(x + off);
      f32x4 b = *(const f32x4*)(x + off + 4);
      o[0] = f2h(a[0]); o[1] = f2h(a[1]); o[2] = f2h(a[2]); o[3] = f2h(a[3]);
      o[4] = f2h(b[0]); o[5] = f2h(b[1]); o[6] = f2h(b[2]); o[7] = f2h(b[3]);
    } else {
      o = (u16x8)0;                       // shadow feature row = zeros
    }
    *(u16x8*)(xh + off) = o;
  } else {
    int t = (blockIdx.x - CVT_BLOCKS) * blockDim.x + threadIdx.x;
    if (t >= 8 * 20 * 64) return;
    int lane = t & 63;
    int frag = t >> 6;            // ct*20 + ks
    int ks = frag % 20;
    int ct = frag / 20;
    int row0 = ks * 32 + (lane >> 4) * 8;
    int col  = ct * 16 + (lane & 15);
    u16x8 o;
    #pragma unroll
    for (int j = 0; j < 8; ++j) o[j] = f2h(w[(row0 + j) * COUT + col]);
    *(u16x8*)(bp + (long)t * 8) = o;
  }
}

// ---- fused kernel: R9 structure + EARLY DEPTH-8 bp PREFETCH -----------------
// R11 decomposition: harness residual is a constant ~73us (prep-trivial run
// proved it); kernel floor = fused dur. R0-vs-fused arithmetic says the GEMM
// phase adds ~20-25us, and its per-iter math shows why: pb[ks&3] is consumed
// ~70cy after issue vs ~200cy L2 latency -> ~130cy stall x 20 iters per wave,
// behind a barrier where inter-wave overlap is weakest. Fix: depth-8 pb ring
// (+16 VGPR; R9 had 36 vs cap 85) with the 8-load prologue issued BEFORE
// phases A2/B/C -- bp is input-independent and L2-resident, so it lands
// thousands of cycles early and doesn't consume HBM miss-queue slots.
//
// LDS layout (smem, 32256 B):
//   [    0, 20480) sA (20 frags x 512 halves, XOR swz); before post-B barrier
//                  first 7040 B double as nbr[16][80] | kp[16][30]
//   [20480, 30464) aw[16][13][12] u32
//   [30464, 32256) offx[16][28] u32 (byte offsets, 2 pad/row for b128 align)
#define NBR(m, c)    (((float*)smem)[(m) * 80 + (c)])
#define KPQ(m, r)    (((float*)(smem + 5120))[(m) * 30 + (r)])
#define AW(m, hp, k) (((unsigned int*)(smem + 20480))[((m) * 13 + (hp)) * 12 + (k)])
#define OFFX(m, h)   (((unsigned int*)(smem + 30464))[(m) * 28 + (h)])

__global__ void __launch_bounds__(512, 6)
kpconv_fused(const float* __restrict__ q_pts, const float* __restrict__ s_pts,
             const float* __restrict__ gen_W, const float* __restrict__ gen_b,
             const int* __restrict__ inds, const unsigned short* __restrict__ xh,
             const unsigned short* __restrict__ bp, float* __restrict__ out) {

  __shared__ char smem[32256] __attribute__((aligned(16)));
  unsigned short* sA = (unsigned short*)smem;
  const char* xb = (const char*)xh;

  const int  tid  = threadIdx.x;
  const int  lane = tid & 63;
  const int  wv   = tid >> 6;                        // 0..7
  const int  m0   = wv * 2;                          // wave-owned rows m0, m0+1
  const long row0 = (long)blockIdx.x * BM;

  // ---- Phase A (per-wave, 1 iter): neighbors = s_pad[ind] - q ----
  if (lane < 2 * NB_H) {
    int m = m0 + lane / NB_H;
    int h = lane % NB_H;
    int n = (int)row0 + m;
    int ind = inds[n * NB_H + h];
    OFFX(m, h) = (unsigned)ind << 7;     // byte offset of row in xh (128 B/row)
    float sx, sy, sz;
    if ((unsigned)ind < (unsigned)N_S) {
      sx = s_pts[ind * 3 + 0]; sy = s_pts[ind * 3 + 1]; sz = s_pts[ind * 3 + 2];
    } else {
      sx = 1e6f; sy = 1e6f; sz = 1e6f;   // shadow support point (xh row = zeros)
    }
    NBR(m, h * 3 + 0) = sx - q_pts[n * 3 + 0];
    NBR(m, h * 3 + 1) = sy - q_pts[n * 3 + 1];
    NBR(m, h * 3 + 2) = sz - q_pts[n * 3 + 2];
  }
  if (lane < 4) NBR(m0 + (lane >> 1), 78 + (lane & 1)) = -1.0f;
  asm volatile("s_waitcnt lgkmcnt(0)" ::: "memory");   // wave-local fence

  // ---- Hoist ALL 26 gather offsets into VGPRs (7 x b128 LDS reads) ----
  const int il   = lane & 31;
  const int g2   = lane >> 5;
  const int i0   = il * 2;
  const int rowc = m0 + g2;                          // this thread's row
  unsigned int voff[26];
  {
    const unsigned int cb = (unsigned)i0 * 2;        // channel byte offset
    u32x4 t[7];
    #pragma unroll
    for (int q = 0; q < 7; ++q) t[q] = *(const u32x4*)&OFFX(rowc, q * 4);
    #pragma unroll
    for (int h = 0; h < 26; ++h) voff[h] = t[h >> 2][h & 3] + cb;
  }

  // ---- Window prefetch h=0..12 (13 HBM-gathers in flight during A2+B) ----
  unsigned int win[13];
  #pragma unroll
  for (int h = 0; h < 13; ++h)
    win[h] = *(const unsigned int*)(xb + voff[h]);

  // ---- EARLY bp prologue: 8 frags issued now, consumed in the GEMM phase.
  // L2-resident (160 KB shared by all blocks) -> lands long before use;
  // issued AFTER the win gathers so HBM misses get the queue first.
  const int ct = wv;                                  // one 16-col tile per wave
  u16x8 pb[8];
  #pragma unroll
  for (int d = 0; d < 8; ++d)
    pb[d] = *(const u16x8*)(bp + (long)((ct * 20 + d) * 64 + lane) * 8);

  // ---- Phase A2 (per-wave, 1 iter): kp = padded @ gen_W^T + gen_b ----
  if (lane < 2 * 30) {
    int m = m0 + lane / 30;
    int r = lane % 30;
    const float* Wr = gen_W + r * (PAD_H * 3);
    const f32x4* W4 = (const f32x4*)Wr;
    const f32x4* N4 = (const f32x4*)&NBR(m, 0);
    f32x4 accv = {0.f, 0.f, 0.f, 0.f};
    #pragma unroll
    for (int j = 0; j < 20; ++j) accv += W4[j] * N4[j];
    KPQ(m, r) = gen_b[r] - (Wr[80] + Wr[81] + Wr[82] + Wr[83])
              + accv[0] + accv[1] + accv[2] + accv[3];
  }
  asm volatile("s_waitcnt lgkmcnt(0)" ::: "memory");   // wave-local fence

  // ---- Phase B (per-wave, 5 iters): w-pairs (h0,h1) per (m,hp,k) ----
  #pragma unroll
  for (int it = 0; it < 5; ++it) {
    int idx = it * 64 + lane;
    if (idx < 2 * 13 * KP) {
      int k  = idx % KP;
      int t  = idx / KP;         // 0..25
      int m  = m0 + (t & 1);
      int hp = t >> 1;           // 0..12
      float kx = KPQ(m, k * 3 + 0), ky = KPQ(m, k * 3 + 1), kz = KPQ(m, k * 3 + 2);
      int h0 = hp * 2;
      float dx0 = NBR(m, h0 * 3 + 0) - kx;
      float dy0 = NBR(m, h0 * 3 + 1) - ky;
      float dz0 = NBR(m, h0 * 3 + 2) - kz;
      float w0 = fmaxf(1.0f - sqrtf(dx0 * dx0 + dy0 * dy0 + dz0 * dz0) * (1.0f / 1.2f), 0.0f);
      float dx1 = NBR(m, h0 * 3 + 3) - kx;
      float dy1 = NBR(m, h0 * 3 + 4) - ky;
      float dz1 = NBR(m, h0 * 3 + 5) - kz;
      float w1 = fmaxf(1.0f - sqrtf(dx1 * dx1 + dy1 * dy1 + dz1 * dz1) * (1.0f / 1.2f), 0.0f);
      AW(m, hp, k) = pkrtz_u32(w0, w1);
    }
  }
  // ---- post-B block barrier: nbr/kp dead for ALL waves; sA may be written.
  // Raw s_barrier (no vmcnt drain) keeps window + bp gathers in flight.
  asm volatile("s_waitcnt lgkmcnt(0)" ::: "memory");
  __builtin_amdgcn_s_barrier();
  asm volatile("" ::: "memory");

  // ---- Phase C (per-thread single row): 13-deep static window; fdot2 ----
  {
    float acc0[KP], acc1[KP];
    #pragma unroll
    for (int k = 0; k < KP; ++k) { acc0[k] = 0.f; acc1[k] = 0.f; }

    #pragma unroll
    for (int p = 0; p < 13; ++p) {
      unsigned int r0 = win[(2 * p) % 13];
      unsigned int r1 = win[(2 * p + 1) % 13];
      if (2 * p + 13 < NB_H)
        win[(2 * p) % 13] = *(const unsigned int*)(xb + voff[2 * p + 13]);
      if (2 * p + 14 < NB_H)
        win[(2 * p + 1) % 13] = *(const unsigned int*)(xb + voff[2 * p + 14]);
      unsigned int p0 = __builtin_amdgcn_perm(r1, r0, 0x05040100u);
      unsigned int p1 = __builtin_amdgcn_perm(r1, r0, 0x07060302u);

      unsigned int wr[KP];
      *(u32x4*)&wr[0] = *(const u32x4*)&AW(rowc, p, 0);
      *(u32x4*)&wr[4] = *(const u32x4*)&AW(rowc, p, 4);
      *(u32x2*)&wr[8] = *(const u32x2*)&AW(rowc, p, 8);

      #pragma unroll
      for (int k = 0; k < KP; ++k) {
        acc0[k] = fdot2u(wr[k], p0, acc0[k]);
        acc1[k] = fdot2u(wr[k], p1, acc1[k]);
      }
    }

    // swizzled frag store (verified R3): slot = kq*16+row;
    // half = slot*8 + j, XOR (kq<<3)^(qhi<<5); +qhi*512 frag parity
    const int kq  = (il & 15) >> 2;
    const int qhi = il >> 4;
    const int j2  = (2 * il) & 7;
    const int swz = (kq << 3) ^ (qhi << 5);
    const int hb  = (((kq * 16 + rowc) * 8 + j2) ^ swz) + qhi * 512;
    #pragma unroll
    for (int k = 0; k < KP; ++k)
      *(unsigned int*)(sA + k * 1024 + hb) = pkrtz_u32(acc0[k], acc1[k]);
  }

  // ---- pre-GEMM block barrier: sA complete (raw, no vmcnt drain) ----
  asm volatile("s_waitcnt lgkmcnt(0)" ::: "memory");
  __builtin_amdgcn_s_barrier();
  asm volatile("" ::: "memory");

  // ---- GEMM: out[16][ct*16..+16] = A[16][640] @ B[640][16] (fp16 MFMA) ----
  // pb ring depth 8: iter ks consumes data issued >=8 iters (or one full
  // gather+compute phase) earlier -> bp L2 latency fully covered.
  {
    const int a0 = (lane * 8) ^ ((lane >> 4) << 3);   // halves within frag

    f32x4 acc = (f32x4){0.f, 0.f, 0.f, 0.f};

    #pragma unroll
    for (int ks = 0; ks < 20; ++ks) {
      f16x8 b = __builtin_bit_cast(f16x8, pb[ks & 7]);
      if (ks + 8 < 20)
        pb[ks & 7] = *(const u16x8*)(bp + (long)((ct * 20 + ks + 8) * 64 + lane) * 8);
      u16x8 au = *(const u16x8*)&sA[ks * 512 + (a0 ^ ((ks & 1) << 5))];
      f16x8 a = __builtin_bit_cast(f16x8, au);
      acc = __builtin_amdgcn_mfma_f32_16x16x32_f16(a, b, acc, 0, 0, 0);
    }

    // C/D layout: col = lane&15, row = (lane>>4)*4 + reg  [measured m89/m91]
    const int col   = lane & 15;
    const int rbase = (lane >> 4) * 4;
    #pragma unroll
    for (int r = 0; r < 4; ++r) {
      long row = row0 + rbase + r;
      __builtin_nontemporal_store(acc[r], &out[row * COUT + ct * 16 + col]);
    }
  }
}

extern "C" void kernel_launch(void* const* d_in, const int* in_sizes, int n_in,
                              void* d_out, int out_size, void* d_ws, size_t ws_size,
                              hipStream_t stream) {
  const float* q_pts = (const float*)d_in[0];
  const float* s_pts = (const float*)d_in[1];
  const float* x     = (const float*)d_in[2];
  const float* gen_W = (const float*)d_in[3];
  const float* gen_b = (const float*)d_in[4];
  const float* wts   = (const float*)d_in[5];
  const int*   inds  = (const int*)d_in[6];
  float* out = (float*)d_out;

  unsigned short* xh = (unsigned short*)d_ws;            // (N_S+1)*CIN fp16 = 8.39 MB
  unsigned short* bp = xh + (size_t)(N_S + 1) * CIN;     // 81920 fp16 = 160 KB

  prep_kernel<<<CVT_BLOCKS + PACK_BLOCKS, 256, 0, stream>>>(x, wts, xh, bp);
  kpconv_fused<<<N_Q / BM, 512, 0, stream>>>(q_pts, s_pts, gen_W, gen_b,
                                             inds, xh, bp, out);
}

// Round 14
// 165.340 us; speedup vs baseline: 1.4854x; 1.4854x over previous
//
#include <hip/hip_runtime.h>
#include <stdint.h>

#define N_Q   65536
#define N_S   65536
#define NB_H  26
#define PAD_H 28
#define KP    10
#define CIN   64
#define COUT  128
#define MT    16   // query points per block
#define BM    16   // output rows per block

typedef unsigned short u16x8  __attribute__((ext_vector_type(8)));
typedef float          f32x4  __attribute__((ext_vector_type(4)));
typedef _Float16       f16x8  __attribute__((ext_vector_type(8)));
typedef _Float16       f16x2  __attribute__((ext_vector_type(2)));
typedef unsigned int   u32x4  __attribute__((ext_vector_type(4)));
typedef unsigned int   u32x2  __attribute__((ext_vector_type(2)));

#define CVT_BLOCKS 2049   // ceil((N_S+1)*CIN/8 / 256)
#define PACK_BLOCKS 40    // ceil(8*20*64 / 256)

static __device__ __forceinline__ unsigned short f2h(float f) {
  return __builtin_bit_cast(unsigned short, (_Float16)f);
}

// v_cvt_pkrtz_f16_f32 packed to raw u32
static __device__ __forceinline__ unsigned int pkrtz_u32(float a, float b) {
  return __builtin_bit_cast(unsigned int, __builtin_amdgcn_cvt_pkrtz(a, b));
}

// half2-dot with fp32 accumulate: v_dot2_f32_f16
static __device__ __forceinline__ float fdot2u(unsigned int a, unsigned int b, float c) {
#if __has_builtin(__builtin_amdgcn_fdot2)
  return __builtin_amdgcn_fdot2(__builtin_bit_cast(f16x2, a),
                                __builtin_bit_cast(f16x2, b), c, false);
#else
  f16x2 ha = __builtin_bit_cast(f16x2, a), hb = __builtin_bit_cast(f16x2, b);
  return c + (float)ha[0] * (float)hb[0] + (float)ha[1] * (float)hb[1];
#endif
}

// ---- prep: x fp32 -> fp16 (+ zero shadow row) AND weight pack (fp16) --------
// Bpack[((ct*20 + ks)*64 + lane)*8 + j] = B[ks*32 + (lane>>4)*8 + j][ct*16 + (lane&15)]
__global__ void prep_kernel(const float* __restrict__ x,
                            const float* __restrict__ w,
                            unsigned short* __restrict__ xh,
                            unsigned short* __restrict__ bp) {
  if (blockIdx.x < CVT_BLOCKS) {
    long t = (long)blockIdx.x * blockDim.x + threadIdx.x;
    long off = t * 8;
    if (off >= (long)(N_S + 1) * CIN) return;
    u16x8 o;
    if (off < (long)N_S * CIN) {
      f32x4 a = *(const f32x4*)(x + off);
      f32x4 b = *(const f32x4*)(x + off + 4);
      o[0] = f2h(a[0]); o[1] = f2h(a[1]); o[2] = f2h(a[2]); o[3] = f2h(a[3]);
      o[4] = f2h(b[0]); o[5] = f2h(b[1]); o[6] = f2h(b[2]); o[7] = f2h(b[3]);
    } else {
      o = (u16x8)0;                       // shadow feature row = zeros
    }
    *(u16x8*)(xh + off) = o;
  } else {
    int t = (blockIdx.x - CVT_BLOCKS) * blockDim.x + threadIdx.x;
    if (t >= 8 * 20 * 64) return;
    int lane = t & 63;
    int frag = t >> 6;            // ct*20 + ks
    int ks = frag % 20;
    int ct = frag / 20;
    int row0 = ks * 32 + (lane >> 4) * 8;
    int col  = ct * 16 + (lane & 15);
    u16x8 o;
    #pragma unroll
    for (int j = 0; j < 8; ++j) o[j] = f2h(w[(row0 + j) * COUT + col]);
    *(u16x8*)(bp + (long)t * 8) = o;
  }
}

// ---- fused kernel: R9 structure (best: 92.8us) + depth-8 pb ring ------------
// R12 lesson (3rd spill): prefetch VGPR cost = width x LIVE RANGE. Issuing
// pb[8] in the prologue spanned the whole gather phase -> spill -> 279MB
// scratch writes. This round the ring is issued at the R5-R9 site (after
// phase C, where win/voff/accs are dead); liveness spans only the pre-GEMM
// barrier + GEMM loop (~55-65 VGPR vs cap 85 at (512,6)). Single variable
// vs R9: ring depth 4 -> 8 (tests the GEMM bp-stall theory validly).
//
// LDS layout (smem, 32256 B):
//   [    0, 20480) sA (20 frags x 512 halves, XOR swz); before post-B barrier
//                  first 7040 B double as nbr[16][80] | kp[16][30]
//   [20480, 30464) aw[16][13][12] u32
//   [30464, 32256) offx[16][28] u32 (byte offsets, 2 pad/row for b128 align)
#define NBR(m, c)    (((float*)smem)[(m) * 80 + (c)])
#define KPQ(m, r)    (((float*)(smem + 5120))[(m) * 30 + (r)])
#define AW(m, hp, k) (((unsigned int*)(smem + 20480))[((m) * 13 + (hp)) * 12 + (k)])
#define OFFX(m, h)   (((unsigned int*)(smem + 30464))[(m) * 28 + (h)])

__global__ void __launch_bounds__(512, 6)
kpconv_fused(const float* __restrict__ q_pts, const float* __restrict__ s_pts,
             const float* __restrict__ gen_W, const float* __restrict__ gen_b,
             const int* __restrict__ inds, const unsigned short* __restrict__ xh,
             const unsigned short* __restrict__ bp, float* __restrict__ out) {

  __shared__ char smem[32256] __attribute__((aligned(16)));
  unsigned short* sA = (unsigned short*)smem;
  const char* xb = (const char*)xh;

  const int  tid  = threadIdx.x;
  const int  lane = tid & 63;
  const int  wv   = tid >> 6;                        // 0..7
  const int  m0   = wv * 2;                          // wave-owned rows m0, m0+1
  const long row0 = (long)blockIdx.x * BM;

  // ---- Phase A (per-wave, 1 iter): neighbors = s_pad[ind] - q ----
  if (lane < 2 * NB_H) {
    int m = m0 + lane / NB_H;
    int h = lane % NB_H;
    int n = (int)row0 + m;
    int ind = inds[n * NB_H + h];
    OFFX(m, h) = (unsigned)ind << 7;     // byte offset of row in xh (128 B/row)
    float sx, sy, sz;
    if ((unsigned)ind < (unsigned)N_S) {
      sx = s_pts[ind * 3 + 0]; sy = s_pts[ind * 3 + 1]; sz = s_pts[ind * 3 + 2];
    } else {
      sx = 1e6f; sy = 1e6f; sz = 1e6f;   // shadow support point (xh row = zeros)
    }
    NBR(m, h * 3 + 0) = sx - q_pts[n * 3 + 0];
    NBR(m, h * 3 + 1) = sy - q_pts[n * 3 + 1];
    NBR(m, h * 3 + 2) = sz - q_pts[n * 3 + 2];
  }
  if (lane < 4) NBR(m0 + (lane >> 1), 78 + (lane & 1)) = -1.0f;
  asm volatile("s_waitcnt lgkmcnt(0)" ::: "memory");   // wave-local fence

  // ---- Hoist ALL 26 gather offsets into VGPRs (7 x b128 LDS reads) ----
  const int il   = lane & 31;
  const int g2   = lane >> 5;
  const int i0   = il * 2;
  const int rowc = m0 + g2;                          // this thread's row
  unsigned int voff[26];
  {
    const unsigned int cb = (unsigned)i0 * 2;        // channel byte offset
    u32x4 t[7];
    #pragma unroll
    for (int q = 0; q < 7; ++q) t[q] = *(const u32x4*)&OFFX(rowc, q * 4);
    #pragma unroll
    for (int h = 0; h < 26; ++h) voff[h] = t[h >> 2][h & 3] + cb;
  }

  // ---- Window prefetch h=0..12 (13 in flight; lands during A2+B) ----
  unsigned int win[13];
  #pragma unroll
  for (int h = 0; h < 13; ++h)
    win[h] = *(const unsigned int*)(xb + voff[h]);

  // ---- Phase A2 (per-wave, 1 iter): kp = padded @ gen_W^T + gen_b ----
  if (lane < 2 * 30) {
    int m = m0 + lane / 30;
    int r = lane % 30;
    const float* Wr = gen_W + r * (PAD_H * 3);
    const f32x4* W4 = (const f32x4*)Wr;
    const f32x4* N4 = (const f32x4*)&NBR(m, 0);
    f32x4 accv = {0.f, 0.f, 0.f, 0.f};
    #pragma unroll
    for (int j = 0; j < 20; ++j) accv += W4[j] * N4[j];
    KPQ(m, r) = gen_b[r] - (Wr[80] + Wr[81] + Wr[82] + Wr[83])
              + accv[0] + accv[1] + accv[2] + accv[3];
  }
  asm volatile("s_waitcnt lgkmcnt(0)" ::: "memory");   // wave-local fence

  // ---- Phase B (per-wave, 5 iters): w-pairs (h0,h1) per (m,hp,k) ----
  #pragma unroll
  for (int it = 0; it < 5; ++it) {
    int idx = it * 64 + lane;
    if (idx < 2 * 13 * KP) {
      int k  = idx % KP;
      int t  = idx / KP;         // 0..25
      int m  = m0 + (t & 1);
      int hp = t >> 1;           // 0..12
      float kx = KPQ(m, k * 3 + 0), ky = KPQ(m, k * 3 + 1), kz = KPQ(m, k * 3 + 2);
      int h0 = hp * 2;
      float dx0 = NBR(m, h0 * 3 + 0) - kx;
      float dy0 = NBR(m, h0 * 3 + 1) - ky;
      float dz0 = NBR(m, h0 * 3 + 2) - kz;
      float w0 = fmaxf(1.0f - sqrtf(dx0 * dx0 + dy0 * dy0 + dz0 * dz0) * (1.0f / 1.2f), 0.0f);
      float dx1 = NBR(m, h0 * 3 + 3) - kx;
      float dy1 = NBR(m, h0 * 3 + 4) - ky;
      float dz1 = NBR(m, h0 * 3 + 5) - kz;
      float w1 = fmaxf(1.0f - sqrtf(dx1 * dx1 + dy1 * dy1 + dz1 * dz1) * (1.0f / 1.2f), 0.0f);
      AW(m, hp, k) = pkrtz_u32(w0, w1);
    }
  }
  // ---- post-B block barrier: nbr/kp dead for ALL waves; sA may be written.
  // Raw s_barrier (no vmcnt drain) keeps window gathers in flight.
  asm volatile("s_waitcnt lgkmcnt(0)" ::: "memory");
  __builtin_amdgcn_s_barrier();
  asm volatile("" ::: "memory");

  // ---- Phase C (per-thread single row): 13-deep static window; fdot2 ----
  {
    float acc0[KP], acc1[KP];
    #pragma unroll
    for (int k = 0; k < KP; ++k) { acc0[k] = 0.f; acc1[k] = 0.f; }

    #pragma unroll
    for (int p = 0; p < 13; ++p) {
      unsigned int r0 = win[(2 * p) % 13];
      unsigned int r1 = win[(2 * p + 1) % 13];
      if (2 * p + 13 < NB_H)
        win[(2 * p) % 13] = *(const unsigned int*)(xb + voff[2 * p + 13]);
      if (2 * p + 14 < NB_H)
        win[(2 * p + 1) % 13] = *(const unsigned int*)(xb + voff[2 * p + 14]);
      unsigned int p0 = __builtin_amdgcn_perm(r1, r0, 0x05040100u);
      unsigned int p1 = __builtin_amdgcn_perm(r1, r0, 0x07060302u);

      unsigned int wr[KP];
      *(u32x4*)&wr[0] = *(const u32x4*)&AW(rowc, p, 0);
      *(u32x4*)&wr[4] = *(const u32x4*)&AW(rowc, p, 4);
      *(u32x2*)&wr[8] = *(const u32x2*)&AW(rowc, p, 8);

      #pragma unroll
      for (int k = 0; k < KP; ++k) {
        acc0[k] = fdot2u(wr[k], p0, acc0[k]);
        acc1[k] = fdot2u(wr[k], p1, acc1[k]);
      }
    }

    // swizzled frag store (verified R3): slot = kq*16+row;
    // half = slot*8 + j, XOR (kq<<3)^(qhi<<5); +qhi*512 frag parity
    const int kq  = (il & 15) >> 2;
    const int qhi = il >> 4;
    const int j2  = (2 * il) & 7;
    const int swz = (kq << 3) ^ (qhi << 5);
    const int hb  = (((kq * 16 + rowc) * 8 + j2) ^ swz) + qhi * 512;
    #pragma unroll
    for (int k = 0; k < KP; ++k)
      *(unsigned int*)(sA + k * 1024 + hb) = pkrtz_u32(acc0[k], acc1[k]);
  }

  // ---- bp depth-8 ring issued HERE (win/voff/accs dead -> liveness spans
  // only the barrier + GEMM loop; ~55-65 VGPR, no spill) ----
  const int ct = wv;                                  // one 16-col tile per wave
  u16x8 pb[8];
  #pragma unroll
  for (int d = 0; d < 8; ++d)
    pb[d] = *(const u16x8*)(bp + (long)((ct * 20 + d) * 64 + lane) * 8);

  // ---- pre-GEMM block barrier: sA complete (raw, no vmcnt drain) ----
  asm volatile("s_waitcnt lgkmcnt(0)" ::: "memory");
  __builtin_amdgcn_s_barrier();
  asm volatile("" ::: "memory");

  // ---- GEMM: out[16][ct*16..+16] = A[16][640] @ B[640][16] (fp16 MFMA) ----
  // Ring depth 8: iter ks consumes data issued >=8 iters earlier (or during
  // the barrier wait) -> bp L2 latency (~200cy) fully covered.
  {
    const int a0 = (lane * 8) ^ ((lane >> 4) << 3);   // halves within frag

    f32x4 acc = (f32x4){0.f, 0.f, 0.f, 0.f};

    #pragma unroll
    for (int ks = 0; ks < 20; ++ks) {
      f16x8 b = __builtin_bit_cast(f16x8, pb[ks & 7]);
      if (ks + 8 < 20)
        pb[ks & 7] = *(const u16x8*)(bp + (long)((ct * 20 + ks + 8) * 64 + lane) * 8);
      u16x8 au = *(const u16x8*)&sA[ks * 512 + (a0 ^ ((ks & 1) << 5))];
      f16x8 a = __builtin_bit_cast(f16x8, au);
      acc = __builtin_amdgcn_mfma_f32_16x16x32_f16(a, b, acc, 0, 0, 0);
    }

    // C/D layout: col = lane&15, row = (lane>>4)*4 + reg  [measured m89/m91]
    const int col   = lane & 15;
    const int rbase = (lane >> 4) * 4;
    #pragma unroll
    for (int r = 0; r < 4; ++r) {
      long row = row0 + rbase + r;
      __builtin_nontemporal_store(acc[r], &out[row * COUT + ct * 16 + col]);
    }
  }
}

extern "C" void kernel_launch(void* const* d_in, const int* in_sizes, int n_in,
                              void* d_out, int out_size, void* d_ws, size_t ws_size,
                              hipStream_t stream) {
  const float* q_pts = (const float*)d_in[0];
  const float* s_pts = (const float*)d_in[1];
  const float* x     = (const float*)d_in[2];
  const float* gen_W = (const float*)d_in[3];
  const float* gen_b = (const float*)d_in[4];
  const float* wts   = (const float*)d_in[5];
  const int*   inds  = (const int*)d_in[6];
  float* out = (float*)d_out;

  unsigned short* xh = (unsigned short*)d_ws;            // (N_S+1)*CIN fp16 = 8.39 MB
  unsigned short* bp = xh + (size_t)(N_S + 1) * CIN;     // 81920 fp16 = 160 KB

  prep_kernel<<<CVT_BLOCKS + PACK_BLOCKS, 256, 0, stream>>>(x, wts, xh, bp);
  kpconv_fused<<<N_Q / BM, 512, 0, stream>>>(q_pts, s_pts, gen_W, gen_b,
                                             inds, xh, bp, out);
}